// Round 12
// baseline (93.233 us; speedup 1.0000x reference)
//
#include <hip/hip_runtime.h>
#include <hip/hip_bf16.h>

typedef __bf16 bf16_t;
typedef __bf16 bf16x8 __attribute__((ext_vector_type(8)));
typedef __bf16 bf16x4 __attribute__((ext_vector_type(4)));
typedef float  f32x4  __attribute__((ext_vector_type(4)));
typedef unsigned int u32x4 __attribute__((ext_vector_type(4)));

#define MFMA16(a,b,c) __builtin_amdgcn_mfma_f32_16x16x32_bf16(a,b,c,0,0,0)

constexpr int B_ = 2, T_ = 2048, H_ = 16, D_ = 64, C_ = 1024;
constexpr int GK = C_;          // GEMM K dim (1024)

// async global->LDS, 16B per lane. LDS dest: wave-uniform base + lane*16.
typedef const __attribute__((address_space(1))) unsigned char ga_t;
typedef __attribute__((address_space(3))) unsigned char la_t;
__device__ __forceinline__ void gld16(const void* g, void* l) {
  __builtin_amdgcn_global_load_lds((ga_t*)g, (la_t*)l, 16, 0, 0);
}

// ---------------- cast fp32 -> bf16 (X, Wq, Wk, Wv, Wp) ----------------
__global__ __launch_bounds__(256) void cast_all(
    const float* __restrict__ X,  const float* __restrict__ Wq,
    const float* __restrict__ Wk, const float* __restrict__ Wv,
    const float* __restrict__ Wp,
    bf16_t* __restrict__ Xb,  bf16_t* __restrict__ Wqb, bf16_t* __restrict__ Wkb,
    bf16_t* __restrict__ Wvb, bf16_t* __restrict__ Wpb)
{
  int i = blockIdx.x * 256 + threadIdx.x;   // each thread converts 4 floats
  const float* src; bf16_t* dst; int off;
  if      (i < 1048576) { src = X;  dst = Xb;  off = i; }
  else if (i < 1310720) { src = Wq; dst = Wqb; off = i - 1048576; }
  else if (i < 1572864) { src = Wk; dst = Wkb; off = i - 1310720; }
  else if (i < 1835008) { src = Wv; dst = Wvb; off = i - 1572864; }
  else                  { src = Wp; dst = Wpb; off = i - 1835008; }
  float4 v = *reinterpret_cast<const float4*>(src + (size_t)off * 4);
  bf16x4 o;
  o[0] = (bf16_t)v.x; o[1] = (bf16_t)v.y; o[2] = (bf16_t)v.z; o[3] = (bf16_t)v.w;
  *reinterpret_cast<bf16x4*>(dst + (size_t)off * 4) = o;
}

// =============================================================================
// 2-phase 128x128 BK=64 core (kept for gemm_proj — its 256-block grid suits it)
// =============================================================================
__device__ __forceinline__ void gemm128_core(
    const bf16_t* __restrict__ A, const bf16_t* __restrict__ Bw,
    bf16_t* sA, bf16_t* sB, f32x4 (&acc)[4][2], int bx, int by)
{
  const int tid = threadIdx.x, lane = tid & 63, wid = tid >> 6;
  const int wm = wid >> 2, wn = wid & 3;
  const int g = lane >> 4, c = lane & 15, rk = c & 7;
  const int srow = tid >> 3;                    // 0..63 rows per 64-row slab
  const int sg   = (tid & 7) ^ (srow & 7);      // pre-swizzled source granule
  const bf16_t* asrc = A  + (size_t)(bx * 128 + srow) * GK + sg * 8;
  const bf16_t* bsrc = Bw + (size_t)(by * 128 + srow) * GK + sg * 8;

  #define STGP(buf, kt)                                                       \
    { char* da = (char*)sA + (buf) * 16384;                                   \
      char* db = (char*)sB + (buf) * 16384;                                   \
      _Pragma("unroll")                                                       \
      for (int it = 0; it < 2; ++it) {                                        \
        gld16(asrc + (size_t)it * 65536 + (kt) * 64, da + (it * 512 + tid) * 16); \
        gld16(bsrc + (size_t)it * 65536 + (kt) * 64, db + (it * 512 + tid) * 16); \
      } }

  #define ITERP(t, buf)                                                       \
    {                                                                         \
      if ((t) < 15) asm volatile("s_waitcnt vmcnt(4)" ::: "memory");          \
      else          asm volatile("s_waitcnt vmcnt(0)" ::: "memory");          \
      __builtin_amdgcn_s_barrier();             /* buf[cur] ready */          \
      const char* ca = (const char*)sA + (buf) * 16384;                       \
      const char* cb = (const char*)sB + (buf) * 16384;                       \
      bf16x8 af[4][2], bfr[2][2];                                             \
      _Pragma("unroll")                                                       \
      for (int mi = 0; mi < 4; ++mi)                                          \
        _Pragma("unroll")                                                     \
        for (int ks = 0; ks < 2; ++ks)                                        \
          af[mi][ks] = *reinterpret_cast<const bf16x8*>(                      \
              ca + (wm * 64 + mi * 16 + c) * 128 + (((ks * 4 + g) ^ rk) * 16)); \
      _Pragma("unroll")                                                       \
      for (int ni = 0; ni < 2; ++ni)                                          \
        _Pragma("unroll")                                                     \
        for (int ks = 0; ks < 2; ++ks)                                        \
          bfr[ni][ks] = *reinterpret_cast<const bf16x8*>(                     \
              cb + (wn * 32 + ni * 16 + c) * 128 + (((ks * 4 + g) ^ rk) * 16)); \
      asm volatile("s_waitcnt lgkmcnt(0)" ::: "memory"); /* my reads done */  \
      __builtin_amdgcn_s_barrier();             /* all reads done */          \
      if ((t) + 2 < 16) STGP(buf, (t) + 2);     /* refill freed buffer */     \
      __builtin_amdgcn_s_setprio(1);                                          \
      _Pragma("unroll")                                                       \
      for (int ks = 0; ks < 2; ++ks)                                          \
        _Pragma("unroll")                                                     \
        for (int mi = 0; mi < 4; ++mi)                                        \
          _Pragma("unroll")                                                   \
          for (int ni = 0; ni < 2; ++ni)                                      \
            acc[mi][ni] = MFMA16(af[mi][ks], bfr[ni][ks], acc[mi][ni]);       \
      __builtin_amdgcn_s_setprio(0);                                          \
    }

  STGP(0, 0);                                   // prologue: 2 tiles in flight
  STGP(1, 1);
  #pragma unroll 1
  for (int t0 = 0; t0 < 16; t0 += 2) {
    ITERP(t0, 0);
    ITERP(t0 + 1, 1);
  }
  #undef ITERP
  #undef STGP
}

// ---------------- fused QKV projection: C[4096,3072] = Xb @ Wqkv^T -----------
// 8-PHASE 256x256 schedule (T3+T4 port of the m201 template — the 2-phase
// structure is ceiling'd at ~640 TF across all R5-R11 variants).
// 512 thr = 8 waves (2M x 4N), wave tile 128x64, acc[8][4], BK=64.
// LDS 128KB = 2 buf x {A-h0,A-h1,B-h0,B-h1} x 16KB. Per K-tile, 4 phases:
//  P1: read A(mi0-3)+B(ni0-1), stage A0(t+1) | P2: read B(ni2-3), stage A1(t+1)
//  P3: read A(mi4-7),          stage B0(t+2) | P4:                stage B1(t+2)
// each phase: issue -> barrier -> lgkmcnt(0) -> setprio+16 MFMA -> barrier.
// Region proof: B-halves of buf b read-complete after P2, A-halves after P3;
// A(t+1) targets the other buffer -> all stages race-free.
// ONE counted vmcnt(4) per tile at tile-start (A1(t) issued at (t-1)P2;
// exactly B0/B1(t+1)=4 loads stay in flight across the barrier; 0 only at tail).
__global__ __launch_bounds__(512, 2) void gemm_qkv(
    const bf16_t* __restrict__ Xb, const bf16_t* __restrict__ Wqkv,
    bf16_t* __restrict__ qo, bf16_t* __restrict__ ko, bf16_t* __restrict__ vto)
{
  __shared__ bf16_t smem_[2][4][128 * 64];      // 128 KB: [buf][A0,A1,B0,B1]
  char* smem = (char*)smem_;
  const int tid = threadIdx.x, lane = tid & 63, wid = tid >> 6;
  const int wm = wid >> 2, wn = wid & 3;        // 2 x 4 wave grid
  const int g = lane >> 4, c = lane & 15, rk = c & 7;
  const int bx = blockIdx.x, by = blockIdx.y;
  const int srow = tid >> 3;                    // 0..63 rows per 64-row slab
  const int sg   = (tid & 7) ^ (srow & 7);      // pre-swizzled source granule
  const bf16_t* asrc = Xb   + (size_t)(bx * 256 + srow) * GK + sg * 8;
  const bf16_t* bsrc = Wqkv + (size_t)(by * 256 + srow) * GK + sg * 8;
  f32x4 acc[8][4] = {};                         // 128 VGPRs

  // stage one 128x64 half-tile (2 gld16/thread)
  #define STG_A(h, kt)                                                        \
    { char* d = smem + ((kt) & 1) * 65536 + (h) * 16384;                      \
      _Pragma("unroll")                                                       \
      for (int it = 0; it < 2; ++it)                                          \
        gld16(asrc + (size_t)((h) * 128 + it * 64) * GK + (kt) * 64,          \
              d + (it * 512 + tid) * 16); }
  #define STG_B(h, kt)                                                        \
    { char* d = smem + ((kt) & 1) * 65536 + 32768 + (h) * 16384;              \
      _Pragma("unroll")                                                       \
      for (int it = 0; it < 2; ++it)                                          \
        gld16(bsrc + (size_t)((h) * 128 + it * 64) * GK + (kt) * 64,          \
              d + (it * 512 + tid) * 16); }

  #define RD_A8(lo)                                                           \
    _Pragma("unroll")                                                         \
    for (int i = 0; i < 4; ++i)                                               \
      _Pragma("unroll")                                                       \
      for (int ks = 0; ks < 2; ++ks)                                          \
        af[i][ks] = *reinterpret_cast<const bf16x8*>(                         \
            ca + (((lo) + i) * 16 + c) * 128 + (((ks * 4 + g) ^ rk) * 16));
  #define RD_B4(lo)                                                           \
    _Pragma("unroll")                                                         \
    for (int i = 0; i < 2; ++i)                                               \
      _Pragma("unroll")                                                       \
      for (int ks = 0; ks < 2; ++ks)                                          \
        bfr[(lo) + i][ks] = *reinterpret_cast<const bf16x8*>(                 \
            cb + (bro + ((lo) + i) * 16 + c) * 128 + (((ks * 4 + g) ^ rk) * 16));
  #define MMQ(alo, nlo)                                                       \
    __builtin_amdgcn_s_setprio(1);                                            \
    _Pragma("unroll")                                                         \
    for (int ks = 0; ks < 2; ++ks)                                            \
      _Pragma("unroll")                                                       \
      for (int i = 0; i < 4; ++i)                                             \
        _Pragma("unroll")                                                     \
        for (int n = 0; n < 2; ++n)                                           \
          acc[(alo) + i][(nlo) + n] =                                         \
              MFMA16(af[i][ks], bfr[(nlo) + n][ks], acc[(alo) + i][(nlo) + n]); \
    __builtin_amdgcn_s_setprio(0);

  // prologue: tile0 (A0,A1,B0,B1) + tile1 (B0,B1) = 12 loads/thread
  STG_A(0, 0); STG_A(1, 0); STG_B(0, 0); STG_B(1, 0);
  STG_B(0, 1); STG_B(1, 1);

  #pragma unroll 1
  for (int t = 0; t < 16; ++t) {
    const int cur = t & 1;
    if (t == 15) asm volatile("s_waitcnt vmcnt(0)" ::: "memory");
    else         asm volatile("s_waitcnt vmcnt(4)" ::: "memory");
    __builtin_amdgcn_s_barrier();               // tile t fully landed
    const char* ca = smem + cur * 65536 + wm * 16384;
    const char* cb = smem + cur * 65536 + 32768 + (wn >> 1) * 16384;
    const int bro = (wn & 1) * 64;
    bf16x8 af[4][2], bfr[4][2];

    // P1: A mi0-3 + B ni0-1 ; stage A0(t+1)
    RD_A8(0) RD_B4(0)
    if (t + 1 < 16) STG_A(0, t + 1);
    __builtin_amdgcn_s_barrier();
    asm volatile("s_waitcnt lgkmcnt(0)" ::: "memory");
    MMQ(0, 0)
    __builtin_amdgcn_s_barrier();
    // P2: B ni2-3 ; stage A1(t+1)
    RD_B4(2)
    if (t + 1 < 16) STG_A(1, t + 1);
    __builtin_amdgcn_s_barrier();
    asm volatile("s_waitcnt lgkmcnt(0)" ::: "memory");
    MMQ(0, 2)
    __builtin_amdgcn_s_barrier();
    // P3: A mi4-7 ; stage B0(t+2)  (B-halves of buf cur free after P2)
    RD_A8(4)
    if (t + 2 < 16) STG_B(0, t + 2);
    __builtin_amdgcn_s_barrier();
    asm volatile("s_waitcnt lgkmcnt(0)" ::: "memory");
    MMQ(4, 2)
    __builtin_amdgcn_s_barrier();
    // P4: stage B1(t+2) ; MFMA on regs held from P1/P3
    if (t + 2 < 16) STG_B(1, t + 2);
    __builtin_amdgcn_s_barrier();
    MMQ(4, 0)
  }
  #undef MMQ
  #undef RD_B4
  #undef RD_A8
  #undef STG_B
  #undef STG_A

  // epilogue: scatter to q / k / v^T. mode uniform per block (by>>2).
  const float qscale = 0.04508422002778f;       // log2(e) * 1024^-0.5
  const int mode = by >> 2;                     // 0=q, 1=k, 2=v
  #pragma unroll
  for (int ni = 0; ni < 4; ++ni) {
    int col = by * 256 + wn * 64 + ni * 16 + c;
    int cm  = col & 1023;
    int h = cm >> 6, d = cm & 63;
    #pragma unroll
    for (int mi = 0; mi < 8; ++mi) {
      int row0 = bx * 256 + wm * 128 + mi * 16 + g * 4;
      int b = row0 >> 11, tt0 = row0 & 2047;
      if (mode == 2) {                          // v: [b,h,d,t] -> t contiguous
        bf16x4 wv;
        #pragma unroll
        for (int r = 0; r < 4; ++r) wv[r] = (bf16_t)acc[mi][ni][r];
        *reinterpret_cast<bf16x4*>(
            &vto[((size_t)(b * H_ + h) * D_ + d) * T_ + tt0]) = wv;
      } else {
        bf16_t* dst = (mode == 0) ? qo : ko;
        float   sc  = (mode == 0) ? qscale : 1.0f;
        #pragma unroll
        for (int r = 0; r < 4; ++r)
          dst[((size_t)(b * H_ + h) * T_ + (tt0 + r)) * D_ + d] =
              (bf16_t)(acc[mi][ni][r] * sc);
      }
    }
  }
}

// ---------------- flash attention (causal) -----------------------------------
// v4 (best measured): 4-wave blocks, counted-vmcnt K/V pipeline, fixed-m
// softmax (m=8 in QK C-in, exp2 domain, cancels in O=PV/l), in-register
// P^T->B-frag via cvt_pk + permlane swaps (no sP LDS).
__global__ __launch_bounds__(256, 4) void attn_fwd(
    const bf16_t* __restrict__ q, const bf16_t* __restrict__ k,
    const bf16_t* __restrict__ vt, bf16_t* __restrict__ att)
{
  __shared__ bf16_t sK[2][64 * 64], sV[2][64 * 64];   // 16KB + 16KB
  const int tid = threadIdx.x, lane = tid & 63, w = tid >> 6;
  const int g = lane >> 4, c = lane & 15;
  const int bid = blockIdx.x;
  const int qt = 31 - (bid >> 5);                     // longest blocks first
  const int bh = bid & 31;
  const bf16_t* qb = q  + (size_t)bh * T_ * D_;
  const bf16_t* kb = k  + (size_t)bh * T_ * D_;
  const bf16_t* vb = vt + (size_t)bh * D_ * T_;       // vt[d][t]

  // Q fragments straight from global (read once)
  bf16x8 qa[2];
  #pragma unroll
  for (int ks = 0; ks < 2; ++ks)
    qa[ks] = *reinterpret_cast<const bf16x8*>(
        qb + (size_t)(qt * 64 + w * 16 + c) * D_ + ks * 32 + g * 8);

  // stage tile kt into buffer buf: 2 K-loads + 2 V-loads per thread (4 gld16)
  const int srow = tid >> 3, sgr0 = tid & 7;
  #define STAGE(buf, kt)                                                        \
    {                                                                           \
      char* kdst = (char*)sK + (size_t)(buf) * 8192;                            \
      char* vdst = (char*)sV + (size_t)(buf) * 8192;                            \
      _Pragma("unroll")                                                         \
      for (int it = 0; it < 2; ++it) {                                          \
        int idx = it * 256 + tid;                                               \
        int row = it * 32 + srow;                                               \
        int sg  = sgr0 ^ (row & 7);                                             \
        gld16(kb + (size_t)((kt) * 64 + row) * D_ + sg * 8, kdst + idx * 16);   \
        gld16(vb + (size_t)row * T_ + (kt) * 64 + sg * 8,   vdst + idx * 16);   \
      }                                                                         \
    }

  STAGE(0, 0);                                        // prologue: 2 in flight
  if (qt >= 1) STAGE(1, 1);

  float l_r = 0.f;                                    // per-lane l (q = c)
  f32x4 acc_t[4] = {};                                // O^T frags [d-block]
  const int rowK = c & 7;                             // swizzle key per lane

  #pragma unroll 1
  for (int kt = 0; kt <= qt; ++kt) {
    const int cur = kt & 1;
    if (kt < qt) asm volatile("s_waitcnt vmcnt(4)" ::: "memory");
    else         asm volatile("s_waitcnt vmcnt(0)" ::: "memory");
    __builtin_amdgcn_s_barrier();                     // buf[cur] ready

    const char* kc = (char*)sK + (size_t)cur * 8192;
    const char* vc = (char*)sV + (size_t)cur * 8192;
    bf16x8 kf[2][4], vf[2][4];
    #pragma unroll
    for (int ks = 0; ks < 2; ++ks)
      #pragma unroll
      for (int f = 0; f < 4; ++f) {
        int rb = (f * 16 + c) * 128;
        int gsw = ((ks * 4 + g) ^ rowK) * 16;
        kf[ks][f] = *reinterpret_cast<const bf16x8*>(kc + rb + gsw);
        vf[ks][f] = *reinterpret_cast<const bf16x8*>(vc + rb + gsw);
      }
    asm volatile("s_waitcnt lgkmcnt(0)" ::: "memory"); // my reads of buf done
    __builtin_amdgcn_s_barrier();                     // all waves' reads done
    if (kt + 2 <= qt) STAGE(cur, kt + 2);             // refill freed buffer

    // S^T - 8 = K Q^T + (-8): fixed-m softmax, m=8 folded into C-in
    f32x4 s[4];
    #pragma unroll
    for (int fj = 0; fj < 4; ++fj) {
      s[fj][0] = -8.f; s[fj][1] = -8.f; s[fj][2] = -8.f; s[fj][3] = -8.f;
    }
    __builtin_amdgcn_s_setprio(1);
    #pragma unroll
    for (int fj = 0; fj < 4; ++fj)
      #pragma unroll
      for (int ks = 0; ks < 2; ++ks)
        s[fj] = MFMA16(kf[ks][fj], qa[ks], s[fj]);
    __builtin_amdgcn_s_setprio(0);

    if (kt == qt) {                                   // causal mask on diagonal
      #pragma unroll
      for (int fj = 0; fj < 4; ++fj)
        #pragma unroll
        for (int r = 0; r < 4; ++r)
          if (fj * 16 + g * 4 + r > w * 16 + c) s[fj][r] = -1e30f;
    }

    // P = exp2(s); pack to bf16 pairs; tree-summed l (1 dependent add)
    unsigned pk[4][2];
    float ls[4];
    #pragma unroll
    for (int fj = 0; fj < 4; ++fj) {
      float pe0 = __builtin_amdgcn_exp2f(s[fj][0]);
      float pe1 = __builtin_amdgcn_exp2f(s[fj][1]);
      float pe2 = __builtin_amdgcn_exp2f(s[fj][2]);
      float pe3 = __builtin_amdgcn_exp2f(s[fj][3]);
      ls[fj] = (pe0 + pe1) + (pe2 + pe3);
      asm("v_cvt_pk_bf16_f32 %0, %1, %2" : "=v"(pk[fj][0]) : "v"(pe0), "v"(pe1));
      asm("v_cvt_pk_bf16_f32 %0, %1, %2" : "=v"(pk[fj][1]) : "v"(pe2), "v"(pe3));
    }
    l_r += (ls[0] + ls[1]) + (ls[2] + ls[3]);

    // in-register P^T -> B-frag redistribution (replaces sP LDS round-trip)
    bf16x8 pf[2];
    #pragma unroll
    for (int ks = 0; ks < 2; ++ks) {
      unsigned x0 = pk[2 * ks][0], y0 = pk[2 * ks + 1][0];
      unsigned x1 = pk[2 * ks][1], y1 = pk[2 * ks + 1][1];
      asm("v_permlane32_swap_b32 %0, %1" : "+v"(x0), "+v"(y0));
      asm("v_permlane32_swap_b32 %0, %1" : "+v"(x1), "+v"(y1));
      asm("v_permlane16_swap_b32 %0, %1" : "+v"(x0), "+v"(y0));
      asm("v_permlane16_swap_b32 %0, %1" : "+v"(x1), "+v"(y1));
      u32x4 t; t[0] = x0; t[1] = x1; t[2] = y0; t[3] = y1;
      pf[ks] = __builtin_bit_cast(bf16x8, t);
    }

    // O^T += V^T P^T
    __builtin_amdgcn_s_setprio(1);
    #pragma unroll
    for (int fd = 0; fd < 4; ++fd)
      #pragma unroll
      for (int ks = 0; ks < 2; ++ks)
        acc_t[fd] = MFMA16(vf[ks][fd], pf[ks], acc_t[fd]);
    __builtin_amdgcn_s_setprio(0);
  }

  // deferred l reduce across the 4 g-groups, then write O
  l_r += __shfl_xor(l_r, 16);
  l_r += __shfl_xor(l_r, 32);
  float inv = 1.0f / l_r;
  const int b = bh >> 4, h = bh & 15;
  const int t = qt * 64 + w * 16 + c;
  #pragma unroll
  for (int fd = 0; fd < 4; ++fd) {
    bf16x4 wv;
    #pragma unroll
    for (int r = 0; r < 4; ++r) wv[r] = (bf16_t)(acc_t[fd][r] * inv);
    int d = fd * 16 + g * 4;
    *reinterpret_cast<bf16x4*>(&att[((size_t)(b * T_ + t) * H_ + h) * D_ + d]) = wv;
  }
  #undef STAGE
}

// ---------------- output projection: out = att @ Wp^T + bp (fp32 out) --------
__global__ __launch_bounds__(512, 2) void gemm_proj(
    const bf16_t* __restrict__ attb, const bf16_t* __restrict__ Wpb,
    const float* __restrict__ bp, float* __restrict__ out)
{
  __shared__ bf16_t sA[2][128 * 64];            // 32 KB
  __shared__ bf16_t sB[2][128 * 64];            // 32 KB
  f32x4 acc[4][2] = {};
  const int bx = blockIdx.x, by = blockIdx.y;
  gemm128_core(attb, Wpb, &sA[0][0], &sB[0][0], acc, bx, by);

  const int tid = threadIdx.x, lane = tid & 63, wid = tid >> 6;
  const int wm = wid >> 2, wn = wid & 3;
  const int g = lane >> 4, c = lane & 15;
  #pragma unroll
  for (int m = 0; m < 4; ++m)
    #pragma unroll
    for (int n = 0; n < 2; ++n)
      #pragma unroll
      for (int r = 0; r < 4; ++r) {
        int row = bx * 128 + wm * 64 + m * 16 + g * 4 + r;
        int col = by * 128 + wn * 32 + n * 16 + c;
        out[(size_t)row * C_ + col] = acc[m][n][r] + bp[col];
      }
}

extern "C" void kernel_launch(void* const* d_in, const int* in_sizes, int n_in,
                              void* d_out, int out_size, void* d_ws, size_t ws_size,
                              hipStream_t stream)
{
  const float* X  = (const float*)d_in[0];
  const float* Wq = (const float*)d_in[1];
  const float* Wk = (const float*)d_in[2];
  const float* Wv = (const float*)d_in[3];
  const float* Wp = (const float*)d_in[4];
  const float* bp = (const float*)d_in[5];
  float* out = (float*)d_out;

  char* ws = (char*)d_ws;
  bf16_t* Xb   = (bf16_t*)(ws);                       // 8 MB  [B*T][C]
  bf16_t* Wqb  = (bf16_t*)(ws + ((size_t)8  << 20));  // 2 MB  (Wq|Wk|Wv contiguous = Wqkv [3072][1024])
  bf16_t* Wkb  = (bf16_t*)(ws + ((size_t)10 << 20));  // 2 MB
  bf16_t* Wvb  = (bf16_t*)(ws + ((size_t)12 << 20));  // 2 MB
  bf16_t* Wpb  = (bf16_t*)(ws + ((size_t)14 << 20));  // 2 MB
  bf16_t* qo   = (bf16_t*)(ws + ((size_t)16 << 20));  // 8 MB  [B,H,T,D] (pre-scaled, exp2 domain)
  bf16_t* ko   = (bf16_t*)(ws + ((size_t)24 << 20));  // 8 MB  [B,H,T,D]
  bf16_t* vto  = (bf16_t*)(ws + ((size_t)32 << 20));  // 8 MB  [B,H,D,T]
  bf16_t* attb = (bf16_t*)(ws + ((size_t)40 << 20));  // 8 MB  [B,T,H*D]

  cast_all<<<8192, 256, 0, stream>>>(X, Wq, Wk, Wv, Wp, Xb, Wqb, Wkb, Wvb, Wpb);
  gemm_qkv<<<dim3(16, 12), 512, 0, stream>>>(Xb, Wqb, qo, ko, vto);
  attn_fwd<<<1024, 256, 0, stream>>>(qo, ko, vto, attb);
  gemm_proj<<<dim3(32, 8), 512, 0, stream>>>(attb, Wpb, bp, out);
}

// Round 13
// 92.268 us; speedup vs baseline: 1.0105x; 1.0105x over previous
//
#include <hip/hip_runtime.h>
#include <hip/hip_bf16.h>

typedef __bf16 bf16_t;
typedef __bf16 bf16x8 __attribute__((ext_vector_type(8)));
typedef __bf16 bf16x4 __attribute__((ext_vector_type(4)));
typedef float  f32x4  __attribute__((ext_vector_type(4)));
typedef unsigned int u32x4 __attribute__((ext_vector_type(4)));
typedef _Float16 f16x4 __attribute__((ext_vector_type(4)));

#define MFMA16(a,b,c) __builtin_amdgcn_mfma_f32_16x16x32_bf16(a,b,c,0,0,0)

constexpr int B_ = 2, T_ = 2048, H_ = 16, D_ = 64, C_ = 1024;
constexpr int GK = C_;          // GEMM K dim (1024)

// async global->LDS, 16B per lane. LDS dest: wave-uniform base + lane*16.
typedef const __attribute__((address_space(1))) unsigned char ga_t;
typedef __attribute__((address_space(3))) unsigned char la_t;
__device__ __forceinline__ void gld16(const void* g, void* l) {
  __builtin_amdgcn_global_load_lds((ga_t*)g, (la_t*)l, 16, 0, 0);
}

// ---------------- cast fp32 -> bf16 (X, Wq, Wk, Wv, Wp) ----------------
__global__ __launch_bounds__(256) void cast_all(
    const float* __restrict__ X,  const float* __restrict__ Wq,
    const float* __restrict__ Wk, const float* __restrict__ Wv,
    const float* __restrict__ Wp,
    bf16_t* __restrict__ Xb,  bf16_t* __restrict__ Wqb, bf16_t* __restrict__ Wkb,
    bf16_t* __restrict__ Wvb, bf16_t* __restrict__ Wpb)
{
  int i = blockIdx.x * 256 + threadIdx.x;   // each thread converts 4 floats
  const float* src; bf16_t* dst; int off;
  if      (i < 1048576) { src = X;  dst = Xb;  off = i; }
  else if (i < 1310720) { src = Wq; dst = Wqb; off = i - 1048576; }
  else if (i < 1572864) { src = Wk; dst = Wkb; off = i - 1310720; }
  else if (i < 1835008) { src = Wv; dst = Wvb; off = i - 1572864; }
  else                  { src = Wp; dst = Wpb; off = i - 1835008; }
  float4 v = *reinterpret_cast<const float4*>(src + (size_t)off * 4);
  bf16x4 o;
  o[0] = (bf16_t)v.x; o[1] = (bf16_t)v.y; o[2] = (bf16_t)v.z; o[3] = (bf16_t)v.w;
  *reinterpret_cast<bf16x4*>(dst + (size_t)off * 4) = o;
}

// =============================================================================
// 2-phase 128x128 BK=64 counted-vmcnt GEMM core (R11 — best measured).
// =============================================================================
__device__ __forceinline__ void gemm128_core(
    const bf16_t* __restrict__ A, const bf16_t* __restrict__ Bw,
    bf16_t* sA, bf16_t* sB, f32x4 (&acc)[4][2], int bx, int by)
{
  const int tid = threadIdx.x, lane = tid & 63, wid = tid >> 6;
  const int wm = wid >> 2, wn = wid & 3;
  const int g = lane >> 4, c = lane & 15, rk = c & 7;
  const int srow = tid >> 3;                    // 0..63 rows per 64-row slab
  const int sg   = (tid & 7) ^ (srow & 7);      // pre-swizzled source granule
  const bf16_t* asrc = A  + (size_t)(bx * 128 + srow) * GK + sg * 8;
  const bf16_t* bsrc = Bw + (size_t)(by * 128 + srow) * GK + sg * 8;

  #define STGP(buf, kt)                                                       \
    { char* da = (char*)sA + (buf) * 16384;                                   \
      char* db = (char*)sB + (buf) * 16384;                                   \
      _Pragma("unroll")                                                       \
      for (int it = 0; it < 2; ++it) {                                        \
        gld16(asrc + (size_t)it * 65536 + (kt) * 64, da + (it * 512 + tid) * 16); \
        gld16(bsrc + (size_t)it * 65536 + (kt) * 64, db + (it * 512 + tid) * 16); \
      } }

  #define ITERP(t, buf)                                                       \
    {                                                                         \
      if ((t) < 15) asm volatile("s_waitcnt vmcnt(4)" ::: "memory");          \
      else          asm volatile("s_waitcnt vmcnt(0)" ::: "memory");          \
      __builtin_amdgcn_s_barrier();             /* buf[cur] ready */          \
      const char* ca = (const char*)sA + (buf) * 16384;                       \
      const char* cb = (const char*)sB + (buf) * 16384;                       \
      bf16x8 af[4][2], bfr[2][2];                                             \
      _Pragma("unroll")                                                       \
      for (int mi = 0; mi < 4; ++mi)                                          \
        _Pragma("unroll")                                                     \
        for (int ks = 0; ks < 2; ++ks)                                        \
          af[mi][ks] = *reinterpret_cast<const bf16x8*>(                      \
              ca + (wm * 64 + mi * 16 + c) * 128 + (((ks * 4 + g) ^ rk) * 16)); \
      _Pragma("unroll")                                                       \
      for (int ni = 0; ni < 2; ++ni)                                          \
        _Pragma("unroll")                                                     \
        for (int ks = 0; ks < 2; ++ks)                                        \
          bfr[ni][ks] = *reinterpret_cast<const bf16x8*>(                     \
              cb + (wn * 32 + ni * 16 + c) * 128 + (((ks * 4 + g) ^ rk) * 16)); \
      asm volatile("s_waitcnt lgkmcnt(0)" ::: "memory"); /* my reads done */  \
      __builtin_amdgcn_s_barrier();             /* all reads done */          \
      if ((t) + 2 < 16) STGP(buf, (t) + 2);     /* refill freed buffer */     \
      __builtin_amdgcn_s_setprio(1);                                          \
      _Pragma("unroll")                                                       \
      for (int ks = 0; ks < 2; ++ks)                                          \
        _Pragma("unroll")                                                     \
        for (int mi = 0; mi < 4; ++mi)                                        \
          _Pragma("unroll")                                                   \
          for (int ni = 0; ni < 2; ++ni)                                      \
            acc[mi][ni] = MFMA16(af[mi][ks], bfr[ni][ks], acc[mi][ni]);       \
      __builtin_amdgcn_s_setprio(0);                                          \
    }

  STGP(0, 0);                                   // prologue: 2 tiles in flight
  STGP(1, 1);
  #pragma unroll 1
  for (int t0 = 0; t0 < 16; t0 += 2) {
    ITERP(t0, 0);
    ITERP(t0 + 1, 1);
  }
  #undef ITERP
  #undef STGP
}

// ---------------- fused QKV projection: C[4096,3072] = Xb @ Wqkv^T -----------
// 128x128 tile (R11 config — best measured), grid 32x24 = 768 blocks.
__global__ __launch_bounds__(512, 2) void gemm_qkv(
    const bf16_t* __restrict__ Xb, const bf16_t* __restrict__ Wqkv,
    bf16_t* __restrict__ qo, bf16_t* __restrict__ ko, bf16_t* __restrict__ vto)
{
  __shared__ bf16_t sA[2][128 * 64];            // 32 KB
  __shared__ bf16_t sB[2][128 * 64];            // 32 KB
  f32x4 acc[4][2] = {};
  const int bx = blockIdx.x, by = blockIdx.y;
  gemm128_core(Xb, Wqkv, &sA[0][0], &sB[0][0], acc, bx, by);

  const int tid = threadIdx.x, lane = tid & 63, wid = tid >> 6;
  const int wm = wid >> 2, wn = wid & 3;
  const int g = lane >> 4, c = lane & 15;
  const float qscale = 0.04508422002778f;       // log2(e) * 1024^-0.5
  const int mode = by >> 3;                     // 0=q, 1=k, 2=v (block-uniform)
  #pragma unroll
  for (int ni = 0; ni < 2; ++ni) {
    int col = by * 128 + wn * 32 + ni * 16 + c;
    int cm  = col & 1023;
    int h = cm >> 6, d = cm & 63;
    #pragma unroll
    for (int mi = 0; mi < 4; ++mi) {
      int row0 = bx * 128 + wm * 64 + mi * 16 + g * 4;
      int b = row0 >> 11, tt0 = row0 & 2047;
      if (mode == 2) {                          // v: [b,h,d,t] -> t contiguous
        bf16x4 wv;
        #pragma unroll
        for (int r = 0; r < 4; ++r) wv[r] = (bf16_t)acc[mi][ni][r];
        *reinterpret_cast<bf16x4*>(
            &vto[((size_t)(b * H_ + h) * D_ + d) * T_ + tt0]) = wv;
      } else {
        bf16_t* dst = (mode == 0) ? qo : ko;
        float   sc  = (mode == 0) ? qscale : 1.0f;
        #pragma unroll
        for (int r = 0; r < 4; ++r)
          dst[((size_t)(b * H_ + h) * T_ + (tt0 + r)) * D_ + d] =
              (bf16_t)(acc[mi][ni][r] * sc);
      }
    }
  }
}

// ---------------- flash attention (causal), split-KV for long tiles ----------
// v4 core + load-balance fix (R12 post-mortem: all 1024 blocks co-resident ->
// makespan = qt=31 block's 32 serial iters, ~52% utilization).
// bid<512: FULL tiles qt 15..0 (<=16 iters), write attb directly (v4 path).
// bid>=512: qt 31..16 split into 2 half-KV blocks (<=17 iters) writing
// UNNORMALIZED fp16 O^T partials + fp32 l partials (fixed-m softmax makes
// partials combine by plain addition). attn_reduce sums + normalizes.
__global__ __launch_bounds__(256, 4) void attn_fwd(
    const bf16_t* __restrict__ q, const bf16_t* __restrict__ k,
    const bf16_t* __restrict__ vt, bf16_t* __restrict__ att,
    _Float16* __restrict__ opart, float* __restrict__ lpart)
{
  __shared__ bf16_t sK[2][64 * 64], sV[2][64 * 64];   // 16KB + 16KB
  const int tid = threadIdx.x, lane = tid & 63, w = tid >> 6;
  const int g = lane >> 4, c = lane & 15;
  const int bid = blockIdx.x;

  int qt, bh, k0, kE, half, tile;
  bool split;
  if (bid < 512) {                                    // full: qt 15..0 (LPT)
    qt = 15 - (bid >> 5); bh = bid & 31;
    k0 = 0; kE = qt; split = false; half = 0; tile = 0;
  } else {                                            // split: qt 31..16 (LPT)
    int sid = bid - 512;
    qt = 31 - (sid >> 6);
    int rem = sid & 63; bh = rem >> 1; half = rem & 1;
    int sp = (qt + 1) >> 1;
    k0 = half ? sp : 0;
    kE = half ? qt : sp - 1;
    split = true;
    tile = (31 - qt) * 32 + bh;
  }

  const bf16_t* qb = q  + (size_t)bh * T_ * D_;
  const bf16_t* kb = k  + (size_t)bh * T_ * D_;
  const bf16_t* vb = vt + (size_t)bh * D_ * T_;       // vt[d][t]

  // Q fragments straight from global (read once)
  bf16x8 qa[2];
  #pragma unroll
  for (int ks = 0; ks < 2; ++ks)
    qa[ks] = *reinterpret_cast<const bf16x8*>(
        qb + (size_t)(qt * 64 + w * 16 + c) * D_ + ks * 32 + g * 8);

  // stage tile kt into buffer buf: 2 K-loads + 2 V-loads per thread (4 gld16)
  const int srow = tid >> 3, sgr0 = tid & 7;
  #define STAGE(buf, kt)                                                        \
    {                                                                           \
      char* kdst = (char*)sK + (size_t)(buf) * 8192;                            \
      char* vdst = (char*)sV + (size_t)(buf) * 8192;                            \
      _Pragma("unroll")                                                         \
      for (int it = 0; it < 2; ++it) {                                          \
        int idx = it * 256 + tid;                                               \
        int row = it * 32 + srow;                                               \
        int sg  = sgr0 ^ (row & 7);                                             \
        gld16(kb + (size_t)((kt) * 64 + row) * D_ + sg * 8, kdst + idx * 16);   \
        gld16(vb + (size_t)row * T_ + (kt) * 64 + sg * 8,   vdst + idx * 16);   \
      }                                                                         \
    }

  STAGE(0, k0);                                       // prologue: 2 in flight
  if (k0 + 1 <= kE) STAGE(1, k0 + 1);

  float l_r = 0.f;                                    // per-lane l (q = c)
  f32x4 acc_t[4] = {};                                // O^T frags [d-block]
  const int rowK = c & 7;                             // swizzle key per lane

  #pragma unroll 1
  for (int kt = k0; kt <= kE; ++kt) {
    const int cur = (kt - k0) & 1;
    if (kt < kE) asm volatile("s_waitcnt vmcnt(4)" ::: "memory");
    else         asm volatile("s_waitcnt vmcnt(0)" ::: "memory");
    __builtin_amdgcn_s_barrier();                     // buf[cur] ready

    const char* kc = (char*)sK + (size_t)cur * 8192;
    const char* vc = (char*)sV + (size_t)cur * 8192;
    bf16x8 kf[2][4], vf[2][4];
    #pragma unroll
    for (int ks = 0; ks < 2; ++ks)
      #pragma unroll
      for (int f = 0; f < 4; ++f) {
        int rb = (f * 16 + c) * 128;
        int gsw = ((ks * 4 + g) ^ rowK) * 16;
        kf[ks][f] = *reinterpret_cast<const bf16x8*>(kc + rb + gsw);
        vf[ks][f] = *reinterpret_cast<const bf16x8*>(vc + rb + gsw);
      }
    asm volatile("s_waitcnt lgkmcnt(0)" ::: "memory"); // my reads of buf done
    __builtin_amdgcn_s_barrier();                     // all waves' reads done
    if (kt + 2 <= kE) STAGE(cur, kt + 2);             // refill freed buffer

    // S^T - 8 = K Q^T + (-8): fixed-m softmax, m=8 folded into C-in
    f32x4 s[4];
    #pragma unroll
    for (int fj = 0; fj < 4; ++fj) {
      s[fj][0] = -8.f; s[fj][1] = -8.f; s[fj][2] = -8.f; s[fj][3] = -8.f;
    }
    __builtin_amdgcn_s_setprio(1);
    #pragma unroll
    for (int fj = 0; fj < 4; ++fj)
      #pragma unroll
      for (int ks = 0; ks < 2; ++ks)
        s[fj] = MFMA16(kf[ks][fj], qa[ks], s[fj]);
    __builtin_amdgcn_s_setprio(0);

    if (kt == qt) {                                   // causal mask on diagonal
      #pragma unroll
      for (int fj = 0; fj < 4; ++fj)
        #pragma unroll
        for (int r = 0; r < 4; ++r)
          if (fj * 16 + g * 4 + r > w * 16 + c) s[fj][r] = -1e30f;
    }

    // P = exp2(s); pack to bf16 pairs; tree-summed l (1 dependent add)
    unsigned pk[4][2];
    float ls[4];
    #pragma unroll
    for (int fj = 0; fj < 4; ++fj) {
      float pe0 = __builtin_amdgcn_exp2f(s[fj][0]);
      float pe1 = __builtin_amdgcn_exp2f(s[fj][1]);
      float pe2 = __builtin_amdgcn_exp2f(s[fj][2]);
      float pe3 = __builtin_amdgcn_exp2f(s[fj][3]);
      ls[fj] = (pe0 + pe1) + (pe2 + pe3);
      asm("v_cvt_pk_bf16_f32 %0, %1, %2" : "=v"(pk[fj][0]) : "v"(pe0), "v"(pe1));
      asm("v_cvt_pk_bf16_f32 %0, %1, %2" : "=v"(pk[fj][1]) : "v"(pe2), "v"(pe3));
    }
    l_r += (ls[0] + ls[1]) + (ls[2] + ls[3]);

    // in-register P^T -> B-frag redistribution (no sP LDS round-trip)
    bf16x8 pf[2];
    #pragma unroll
    for (int ks = 0; ks < 2; ++ks) {
      unsigned x0 = pk[2 * ks][0], y0 = pk[2 * ks + 1][0];
      unsigned x1 = pk[2 * ks][1], y1 = pk[2 * ks + 1][1];
      asm("v_permlane32_swap_b32 %0, %1" : "+v"(x0), "+v"(y0));
      asm("v_permlane32_swap_b32 %0, %1" : "+v"(x1), "+v"(y1));
      asm("v_permlane16_swap_b32 %0, %1" : "+v"(x0), "+v"(y0));
      asm("v_permlane16_swap_b32 %0, %1" : "+v"(x1), "+v"(y1));
      u32x4 t; t[0] = x0; t[1] = x1; t[2] = y0; t[3] = y1;
      pf[ks] = __builtin_bit_cast(bf16x8, t);
    }

    // O^T += V^T P^T
    __builtin_amdgcn_s_setprio(1);
    #pragma unroll
    for (int fd = 0; fd < 4; ++fd)
      #pragma unroll
      for (int ks = 0; ks < 2; ++ks)
        acc_t[fd] = MFMA16(vf[ks][fd], pf[ks], acc_t[fd]);
    __builtin_amdgcn_s_setprio(0);
  }

  // l reduce across the 4 g-groups (lanes c, c+16, c+32, c+48)
  l_r += __shfl_xor(l_r, 16);
  l_r += __shfl_xor(l_r, 32);

  if (!split) {                                       // normalized direct write
    float inv = 1.0f / l_r;
    const int b = bh >> 4, h = bh & 15;
    const int t = qt * 64 + w * 16 + c;
    #pragma unroll
    for (int fd = 0; fd < 4; ++fd) {
      bf16x4 wv;
      #pragma unroll
      for (int r = 0; r < 4; ++r) wv[r] = (bf16_t)(acc_t[fd][r] * inv);
      int d = fd * 16 + g * 4;
      *reinterpret_cast<bf16x4*>(&att[((size_t)(b * T_ + t) * H_ + h) * D_ + d]) = wv;
    }
  } else {                                            // unnormalized partials
    size_t obase = ((size_t)(half * 512 + tile) * 256 + tid) * 16;  // f16 elems
    #pragma unroll
    for (int fd = 0; fd < 4; ++fd) {
      f16x4 hv;
      #pragma unroll
      for (int r = 0; r < 4; ++r) hv[r] = (_Float16)acc_t[fd][r];
      *reinterpret_cast<f16x4*>(opart + obase + fd * 4) = hv;
    }
    if (g == 0) lpart[(half * 512 + tile) * 64 + w * 16 + c] = l_r;
  }
  #undef STAGE
}

// ---------------- combine split-tile partials: O=(O0+O1)/(l0+l1) -------------
__global__ __launch_bounds__(256) void attn_reduce(
    const _Float16* __restrict__ opart, const float* __restrict__ lpart,
    bf16_t* __restrict__ att)
{
  const int tile = blockIdx.x;                        // 0..511
  const int qt = 31 - (tile >> 5), bh = tile & 31;
  const int tid = threadIdx.x, lane = tid & 63, w = tid >> 6;
  const int g = lane >> 4, c = lane & 15;
  const size_t o0 = ((size_t)tile * 256 + tid) * 16;
  const size_t o1 = ((size_t)(512 + tile) * 256 + tid) * 16;
  float l = lpart[tile * 64 + w * 16 + c] + lpart[(512 + tile) * 64 + w * 16 + c];
  float inv = 1.0f / l;
  const int b = bh >> 4, h = bh & 15;
  const int t = qt * 64 + w * 16 + c;
  #pragma unroll
  for (int fd = 0; fd < 4; ++fd) {
    f16x4 a = *reinterpret_cast<const f16x4*>(opart + o0 + fd * 4);
    f16x4 bq = *reinterpret_cast<const f16x4*>(opart + o1 + fd * 4);
    bf16x4 wv;
    #pragma unroll
    for (int r = 0; r < 4; ++r)
      wv[r] = (bf16_t)(((float)a[r] + (float)bq[r]) * inv);
    int d = fd * 16 + g * 4;
    *reinterpret_cast<bf16x4*>(&att[((size_t)(b * T_ + t) * H_ + h) * D_ + d]) = wv;
  }
}

// ---------------- output projection: out = att @ Wp^T + bp (fp32 out) --------
__global__ __launch_bounds__(512, 2) void gemm_proj(
    const bf16_t* __restrict__ attb, const bf16_t* __restrict__ Wpb,
    const float* __restrict__ bp, float* __restrict__ out)
{
  __shared__ bf16_t sA[2][128 * 64];            // 32 KB
  __shared__ bf16_t sB[2][128 * 64];            // 32 KB
  f32x4 acc[4][2] = {};
  const int bx = blockIdx.x, by = blockIdx.y;
  gemm128_core(attb, Wpb, &sA[0][0], &sB[0][0], acc, bx, by);

  const int tid = threadIdx.x, lane = tid & 63, wid = tid >> 6;
  const int wm = wid >> 2, wn = wid & 3;
  const int g = lane >> 4, c = lane & 15;
  #pragma unroll
  for (int m = 0; m < 4; ++m)
    #pragma unroll
    for (int n = 0; n < 2; ++n)
      #pragma unroll
      for (int r = 0; r < 4; ++r) {
        int row = bx * 128 + wm * 64 + m * 16 + g * 4 + r;
        int col = by * 128 + wn * 32 + n * 16 + c;
        out[(size_t)row * C_ + col] = acc[m][n][r] + bp[col];
      }
}

extern "C" void kernel_launch(void* const* d_in, const int* in_sizes, int n_in,
                              void* d_out, int out_size, void* d_ws, size_t ws_size,
                              hipStream_t stream)
{
  const float* X  = (const float*)d_in[0];
  const float* Wq = (const float*)d_in[1];
  const float* Wk = (const float*)d_in[2];
  const float* Wv = (const float*)d_in[3];
  const float* Wp = (const float*)d_in[4];
  const float* bp = (const float*)d_in[5];
  float* out = (float*)d_out;

  char* ws = (char*)d_ws;
  bf16_t* Xb   = (bf16_t*)(ws);                       // 8 MB  [B*T][C]
  bf16_t* Wqb  = (bf16_t*)(ws + ((size_t)8  << 20));  // 2 MB  (Wq|Wk|Wv contiguous = Wqkv [3072][1024])
  bf16_t* Wkb  = (bf16_t*)(ws + ((size_t)10 << 20));  // 2 MB
  bf16_t* Wvb  = (bf16_t*)(ws + ((size_t)12 << 20));  // 2 MB
  bf16_t* Wpb  = (bf16_t*)(ws + ((size_t)14 << 20));  // 2 MB
  bf16_t* qo   = (bf16_t*)(ws + ((size_t)16 << 20));  // 8 MB  [B,H,T,D] (pre-scaled, exp2 domain)
  bf16_t* ko   = (bf16_t*)(ws + ((size_t)24 << 20));  // 8 MB  [B,H,T,D]
  bf16_t* vto  = (bf16_t*)(ws + ((size_t)32 << 20));  // 8 MB  [B,H,D,T]
  bf16_t* attb = (bf16_t*)(ws + ((size_t)40 << 20));  // 8 MB  [B,T,H*D]
  // attn split partials REUSE regions dead after gemm_qkv (Xb + Wqb/Wkb):
  _Float16* opart = (_Float16*)(ws);                  // 8 MB  [2][512][256][16] f16
  float*    lpart = (float*)(ws + ((size_t)8 << 20)); // 256KB [2][512][64] f32

  cast_all<<<8192, 256, 0, stream>>>(X, Wq, Wk, Wv, Wp, Xb, Wqb, Wkb, Wvb, Wpb);
  gemm_qkv<<<dim3(32, 24), 512, 0, stream>>>(Xb, Wqb, qo, ko, vto);
  attn_fwd<<<1536, 256, 0, stream>>>(qo, ko, vto, attb, opart, lpart);
  attn_reduce<<<512, 256, 0, stream>>>(opart, lpart, attb);
  gemm_proj<<<dim3(32, 8), 512, 0, stream>>>(attb, Wpb, bp, out);
}

// Round 14
// 88.129 us; speedup vs baseline: 1.0579x; 1.0470x over previous
//
#include <hip/hip_runtime.h>
#include <hip/hip_bf16.h>

typedef __bf16 bf16_t;
typedef __bf16 bf16x8 __attribute__((ext_vector_type(8)));
typedef __bf16 bf16x4 __attribute__((ext_vector_type(4)));
typedef float  f32x4  __attribute__((ext_vector_type(4)));
typedef unsigned int u32x4 __attribute__((ext_vector_type(4)));

#define MFMA16(a,b,c) __builtin_amdgcn_mfma_f32_16x16x32_bf16(a,b,c,0,0,0)

constexpr int B_ = 2, T_ = 2048, H_ = 16, D_ = 64, C_ = 1024;
constexpr int GK = C_;          // GEMM K dim (1024)

// async global->LDS, 16B per lane. LDS dest: wave-uniform base + lane*16.
typedef const __attribute__((address_space(1))) unsigned char ga_t;
typedef __attribute__((address_space(3))) unsigned char la_t;
__device__ __forceinline__ void gld16(const void* g, void* l) {
  __builtin_amdgcn_global_load_lds((ga_t*)g, (la_t*)l, 16, 0, 0);
}

// ---------------- cast fp32 -> bf16 (X, Wq, Wk, Wv, Wp) ----------------
__global__ __launch_bounds__(256) void cast_all(
    const float* __restrict__ X,  const float* __restrict__ Wq,
    const float* __restrict__ Wk, const float* __restrict__ Wv,
    const float* __restrict__ Wp,
    bf16_t* __restrict__ Xb,  bf16_t* __restrict__ Wqb, bf16_t* __restrict__ Wkb,
    bf16_t* __restrict__ Wvb, bf16_t* __restrict__ Wpb)
{
  int i = blockIdx.x * 256 + threadIdx.x;   // each thread converts 4 floats
  const float* src; bf16_t* dst; int off;
  if      (i < 1048576) { src = X;  dst = Xb;  off = i; }
  else if (i < 1310720) { src = Wq; dst = Wqb; off = i - 1048576; }
  else if (i < 1572864) { src = Wk; dst = Wkb; off = i - 1310720; }
  else if (i < 1835008) { src = Wv; dst = Wvb; off = i - 1572864; }
  else                  { src = Wp; dst = Wpb; off = i - 1835008; }
  float4 v = *reinterpret_cast<const float4*>(src + (size_t)off * 4);
  bf16x4 o;
  o[0] = (bf16_t)v.x; o[1] = (bf16_t)v.y; o[2] = (bf16_t)v.z; o[3] = (bf16_t)v.w;
  *reinterpret_cast<bf16x4*>(dst + (size_t)off * 4) = o;
}

// =============================================================================
// 4-wave 128x128 BK=64 counted-vmcnt GEMM core (m97/m103 wave geometry:
// 4 waves (2x2), wave-tile 64x64, acc[4][4] -> 32 MFMA : 16 ds_read_b128 per
// wave per K-step (ratio 2.0 vs the 8-wave core's 1.33), half the lockstep
// group per barrier. 256 threads stage 8 gld16 each -> steady vmcnt(8).
// LDS 64KB -> 2 blocks/CU.
// =============================================================================
__device__ __forceinline__ void gemm128x4_core(
    const bf16_t* __restrict__ A, const bf16_t* __restrict__ Bw,
    bf16_t* sA, bf16_t* sB, f32x4 (&acc)[4][4], int bx, int by)
{
  const int tid = threadIdx.x, lane = tid & 63, wid = tid >> 6;
  const int wm = wid >> 1, wn = wid & 1;        // 2 x 2 wave grid
  const int g = lane >> 4, c = lane & 15, rk = c & 7;
  const int srow = tid >> 3;                    // 0..31 rows per 32-row slab
  const int sg   = (tid & 7) ^ (srow & 7);      // pre-swizzled source granule
  const bf16_t* asrc = A  + (size_t)(bx * 128 + srow) * GK + sg * 8;
  const bf16_t* bsrc = Bw + (size_t)(by * 128 + srow) * GK + sg * 8;

  // stage K-tile kt: 4 A-slabs + 4 B-slabs of 32 rows, 8 gld16/thread
  #define STGP(buf, kt)                                                       \
    { char* da = (char*)sA + (buf) * 16384;                                   \
      char* db = (char*)sB + (buf) * 16384;                                   \
      _Pragma("unroll")                                                       \
      for (int it = 0; it < 4; ++it) {                                        \
        gld16(asrc + (size_t)it * 32768 + (kt) * 64, da + (it * 256 + tid) * 16); \
        gld16(bsrc + (size_t)it * 32768 + (kt) * 64, db + (it * 256 + tid) * 16); \
      } }

  #define ITERP(t, buf)                                                       \
    {                                                                         \
      if ((t) < 15) asm volatile("s_waitcnt vmcnt(8)" ::: "memory");          \
      else          asm volatile("s_waitcnt vmcnt(0)" ::: "memory");          \
      __builtin_amdgcn_s_barrier();             /* buf[cur] ready */          \
      const char* ca = (const char*)sA + (buf) * 16384;                       \
      const char* cb = (const char*)sB + (buf) * 16384;                       \
      bf16x8 af[4][2], bfr[4][2];                                             \
      _Pragma("unroll")                                                       \
      for (int mi = 0; mi < 4; ++mi)                                          \
        _Pragma("unroll")                                                     \
        for (int ks = 0; ks < 2; ++ks)                                        \
          af[mi][ks] = *reinterpret_cast<const bf16x8*>(                      \
              ca + (wm * 64 + mi * 16 + c) * 128 + (((ks * 4 + g) ^ rk) * 16)); \
      _Pragma("unroll")                                                       \
      for (int ni = 0; ni < 4; ++ni)                                          \
        _Pragma("unroll")                                                     \
        for (int ks = 0; ks < 2; ++ks)                                        \
          bfr[ni][ks] = *reinterpret_cast<const bf16x8*>(                     \
              cb + (wn * 64 + ni * 16 + c) * 128 + (((ks * 4 + g) ^ rk) * 16)); \
      asm volatile("s_waitcnt lgkmcnt(0)" ::: "memory"); /* my reads done */  \
      __builtin_amdgcn_s_barrier();             /* all reads done */          \
      if ((t) + 2 < 16) STGP(buf, (t) + 2);     /* refill freed buffer */     \
      __builtin_amdgcn_s_setprio(1);                                          \
      _Pragma("unroll")                                                       \
      for (int ks = 0; ks < 2; ++ks)                                          \
        _Pragma("unroll")                                                     \
        for (int mi = 0; mi < 4; ++mi)                                        \
          _Pragma("unroll")                                                   \
          for (int ni = 0; ni < 4; ++ni)                                      \
            acc[mi][ni] = MFMA16(af[mi][ks], bfr[ni][ks], acc[mi][ni]);       \
      __builtin_amdgcn_s_setprio(0);                                          \
    }

  STGP(0, 0);                                   // prologue: 2 tiles in flight
  STGP(1, 1);
  #pragma unroll 1
  for (int t0 = 0; t0 < 16; t0 += 2) {
    ITERP(t0, 0);
    ITERP(t0 + 1, 1);
  }
  #undef ITERP
  #undef STGP
}

// ---------------- fused QKV projection: C[4096,3072] = Xb @ Wqkv^T -----------
// 128x128 tile, 4-wave core, grid 32x24 = 768 blocks.
__global__ __launch_bounds__(256, 2) void gemm_qkv(
    const bf16_t* __restrict__ Xb, const bf16_t* __restrict__ Wqkv,
    bf16_t* __restrict__ qo, bf16_t* __restrict__ ko, bf16_t* __restrict__ vto)
{
  __shared__ bf16_t sA[2][128 * 64];            // 32 KB
  __shared__ bf16_t sB[2][128 * 64];            // 32 KB
  f32x4 acc[4][4] = {};
  const int bx = blockIdx.x, by = blockIdx.y;
  gemm128x4_core(Xb, Wqkv, &sA[0][0], &sB[0][0], acc, bx, by);

  const int tid = threadIdx.x, lane = tid & 63, wid = tid >> 6;
  const int wm = wid >> 1, wn = wid & 1;
  const int g = lane >> 4, c = lane & 15;
  const float qscale = 0.04508422002778f;       // log2(e) * 1024^-0.5
  const int mode = by >> 3;                     // 0=q, 1=k, 2=v (block-uniform)
  #pragma unroll
  for (int ni = 0; ni < 4; ++ni) {
    int col = by * 128 + wn * 64 + ni * 16 + c;
    int cm  = col & 1023;
    int h = cm >> 6, d = cm & 63;
    #pragma unroll
    for (int mi = 0; mi < 4; ++mi) {
      int row0 = bx * 128 + wm * 64 + mi * 16 + g * 4;
      int b = row0 >> 11, tt0 = row0 & 2047;
      if (mode == 2) {                          // v: [b,h,d,t] -> t contiguous
        bf16x4 wv;
        #pragma unroll
        for (int r = 0; r < 4; ++r) wv[r] = (bf16_t)acc[mi][ni][r];
        *reinterpret_cast<bf16x4*>(
            &vto[((size_t)(b * H_ + h) * D_ + d) * T_ + tt0]) = wv;
      } else {
        bf16_t* dst = (mode == 0) ? qo : ko;
        float   sc  = (mode == 0) ? qscale : 1.0f;
        #pragma unroll
        for (int r = 0; r < 4; ++r)
          dst[((size_t)(b * H_ + h) * T_ + (tt0 + r)) * D_ + d] =
              (bf16_t)(acc[mi][ni][r] * sc);
      }
    }
  }
}

// ---------------- flash attention (causal) -----------------------------------
// v4 (reverted from R13 split-KV regression — best measured attn):
// 4-wave blocks, counted-vmcnt K/V pipeline, fixed-m softmax (m=8 in QK C-in,
// exp2 domain, cancels in O=PV/l), in-register P^T->B-frag via cvt_pk +
// permlane swaps (no sP LDS).
__global__ __launch_bounds__(256, 4) void attn_fwd(
    const bf16_t* __restrict__ q, const bf16_t* __restrict__ k,
    const bf16_t* __restrict__ vt, bf16_t* __restrict__ att)
{
  __shared__ bf16_t sK[2][64 * 64], sV[2][64 * 64];   // 16KB + 16KB
  const int tid = threadIdx.x, lane = tid & 63, w = tid >> 6;
  const int g = lane >> 4, c = lane & 15;
  const int bid = blockIdx.x;
  const int qt = 31 - (bid >> 5);                     // longest blocks first
  const int bh = bid & 31;
  const bf16_t* qb = q  + (size_t)bh * T_ * D_;
  const bf16_t* kb = k  + (size_t)bh * T_ * D_;
  const bf16_t* vb = vt + (size_t)bh * D_ * T_;       // vt[d][t]

  // Q fragments straight from global (read once)
  bf16x8 qa[2];
  #pragma unroll
  for (int ks = 0; ks < 2; ++ks)
    qa[ks] = *reinterpret_cast<const bf16x8*>(
        qb + (size_t)(qt * 64 + w * 16 + c) * D_ + ks * 32 + g * 8);

  // stage tile kt into buffer buf: 2 K-loads + 2 V-loads per thread (4 gld16)
  const int srow = tid >> 3, sgr0 = tid & 7;
  #define STAGE(buf, kt)                                                        \
    {                                                                           \
      char* kdst = (char*)sK + (size_t)(buf) * 8192;                            \
      char* vdst = (char*)sV + (size_t)(buf) * 8192;                            \
      _Pragma("unroll")                                                         \
      for (int it = 0; it < 2; ++it) {                                          \
        int idx = it * 256 + tid;                                               \
        int row = it * 32 + srow;                                               \
        int sg  = sgr0 ^ (row & 7);                                             \
        gld16(kb + (size_t)((kt) * 64 + row) * D_ + sg * 8, kdst + idx * 16);   \
        gld16(vb + (size_t)row * T_ + (kt) * 64 + sg * 8,   vdst + idx * 16);   \
      }                                                                         \
    }

  STAGE(0, 0);                                        // prologue: 2 in flight
  if (qt >= 1) STAGE(1, 1);

  float l_r = 0.f;                                    // per-lane l (q = c)
  f32x4 acc_t[4] = {};                                // O^T frags [d-block]
  const int rowK = c & 7;                             // swizzle key per lane

  #pragma unroll 1
  for (int kt = 0; kt <= qt; ++kt) {
    const int cur = kt & 1;
    if (kt < qt) asm volatile("s_waitcnt vmcnt(4)" ::: "memory");
    else         asm volatile("s_waitcnt vmcnt(0)" ::: "memory");
    __builtin_amdgcn_s_barrier();                     // buf[cur] ready

    const char* kc = (char*)sK + (size_t)cur * 8192;
    const char* vc = (char*)sV + (size_t)cur * 8192;
    bf16x8 kf[2][4], vf[2][4];
    #pragma unroll
    for (int ks = 0; ks < 2; ++ks)
      #pragma unroll
      for (int f = 0; f < 4; ++f) {
        int rb = (f * 16 + c) * 128;
        int gsw = ((ks * 4 + g) ^ rowK) * 16;
        kf[ks][f] = *reinterpret_cast<const bf16x8*>(kc + rb + gsw);
        vf[ks][f] = *reinterpret_cast<const bf16x8*>(vc + rb + gsw);
      }
    asm volatile("s_waitcnt lgkmcnt(0)" ::: "memory"); // my reads of buf done
    __builtin_amdgcn_s_barrier();                     // all waves' reads done
    if (kt + 2 <= qt) STAGE(cur, kt + 2);             // refill freed buffer

    // S^T - 8 = K Q^T + (-8): fixed-m softmax, m=8 folded into C-in
    f32x4 s[4];
    #pragma unroll
    for (int fj = 0; fj < 4; ++fj) {
      s[fj][0] = -8.f; s[fj][1] = -8.f; s[fj][2] = -8.f; s[fj][3] = -8.f;
    }
    __builtin_amdgcn_s_setprio(1);
    #pragma unroll
    for (int fj = 0; fj < 4; ++fj)
      #pragma unroll
      for (int ks = 0; ks < 2; ++ks)
        s[fj] = MFMA16(kf[ks][fj], qa[ks], s[fj]);
    __builtin_amdgcn_s_setprio(0);

    if (kt == qt) {                                   // causal mask on diagonal
      #pragma unroll
      for (int fj = 0; fj < 4; ++fj)
        #pragma unroll
        for (int r = 0; r < 4; ++r)
          if (fj * 16 + g * 4 + r > w * 16 + c) s[fj][r] = -1e30f;
    }

    // P = exp2(s); pack to bf16 pairs; tree-summed l (1 dependent add)
    unsigned pk[4][2];
    float ls[4];
    #pragma unroll
    for (int fj = 0; fj < 4; ++fj) {
      float pe0 = __builtin_amdgcn_exp2f(s[fj][0]);
      float pe1 = __builtin_amdgcn_exp2f(s[fj][1]);
      float pe2 = __builtin_amdgcn_exp2f(s[fj][2]);
      float pe3 = __builtin_amdgcn_exp2f(s[fj][3]);
      ls[fj] = (pe0 + pe1) + (pe2 + pe3);
      asm("v_cvt_pk_bf16_f32 %0, %1, %2" : "=v"(pk[fj][0]) : "v"(pe0), "v"(pe1));
      asm("v_cvt_pk_bf16_f32 %0, %1, %2" : "=v"(pk[fj][1]) : "v"(pe2), "v"(pe3));
    }
    l_r += (ls[0] + ls[1]) + (ls[2] + ls[3]);

    // in-register P^T -> B-frag redistribution (replaces sP LDS round-trip)
    bf16x8 pf[2];
    #pragma unroll
    for (int ks = 0; ks < 2; ++ks) {
      unsigned x0 = pk[2 * ks][0], y0 = pk[2 * ks + 1][0];
      unsigned x1 = pk[2 * ks][1], y1 = pk[2 * ks + 1][1];
      asm("v_permlane32_swap_b32 %0, %1" : "+v"(x0), "+v"(y0));
      asm("v_permlane32_swap_b32 %0, %1" : "+v"(x1), "+v"(y1));
      asm("v_permlane16_swap_b32 %0, %1" : "+v"(x0), "+v"(y0));
      asm("v_permlane16_swap_b32 %0, %1" : "+v"(x1), "+v"(y1));
      u32x4 t; t[0] = x0; t[1] = x1; t[2] = y0; t[3] = y1;
      pf[ks] = __builtin_bit_cast(bf16x8, t);
    }

    // O^T += V^T P^T
    __builtin_amdgcn_s_setprio(1);
    #pragma unroll
    for (int fd = 0; fd < 4; ++fd)
      #pragma unroll
      for (int ks = 0; ks < 2; ++ks)
        acc_t[fd] = MFMA16(vf[ks][fd], pf[ks], acc_t[fd]);
    __builtin_amdgcn_s_setprio(0);
  }

  // deferred l reduce across the 4 g-groups, then write O
  l_r += __shfl_xor(l_r, 16);
  l_r += __shfl_xor(l_r, 32);
  float inv = 1.0f / l_r;
  const int b = bh >> 4, h = bh & 15;
  const int t = qt * 64 + w * 16 + c;
  #pragma unroll
  for (int fd = 0; fd < 4; ++fd) {
    bf16x4 wv;
    #pragma unroll
    for (int r = 0; r < 4; ++r) wv[r] = (bf16_t)(acc_t[fd][r] * inv);
    int d = fd * 16 + g * 4;
    *reinterpret_cast<bf16x4*>(&att[((size_t)(b * T_ + t) * H_ + h) * D_ + d]) = wv;
  }
  #undef STAGE
}

// ---------------- output projection: out = att @ Wp^T + bp (fp32 out) --------
// 4-wave core, grid 32x8 = 256 blocks = exactly one round at 2 blk/CU.
__global__ __launch_bounds__(256, 2) void gemm_proj(
    const bf16_t* __restrict__ attb, const bf16_t* __restrict__ Wpb,
    const float* __restrict__ bp, float* __restrict__ out)
{
  __shared__ bf16_t sA[2][128 * 64];            // 32 KB
  __shared__ bf16_t sB[2][128 * 64];            // 32 KB
  f32x4 acc[4][4] = {};
  const int bx = blockIdx.x, by = blockIdx.y;
  gemm128x4_core(attb, Wpb, &sA[0][0], &sB[0][0], acc, bx, by);

  const int tid = threadIdx.x, lane = tid & 63, wid = tid >> 6;
  const int wm = wid >> 1, wn = wid & 1;
  const int g = lane >> 4, c = lane & 15;
  #pragma unroll
  for (int m = 0; m < 4; ++m)
    #pragma unroll
    for (int n = 0; n < 4; ++n)
      #pragma unroll
      for (int r = 0; r < 4; ++r) {
        int row = bx * 128 + wm * 64 + m * 16 + g * 4 + r;
        int col = by * 128 + wn * 64 + n * 16 + c;
        out[(size_t)row * C_ + col] = acc[m][n][r] + bp[col];
      }
}

extern "C" void kernel_launch(void* const* d_in, const int* in_sizes, int n_in,
                              void* d_out, int out_size, void* d_ws, size_t ws_size,
                              hipStream_t stream)
{
  const float* X  = (const float*)d_in[0];
  const float* Wq = (const float*)d_in[1];
  const float* Wk = (const float*)d_in[2];
  const float* Wv = (const float*)d_in[3];
  const float* Wp = (const float*)d_in[4];
  const float* bp = (const float*)d_in[5];
  float* out = (float*)d_out;

  char* ws = (char*)d_ws;
  bf16_t* Xb   = (bf16_t*)(ws);                       // 8 MB  [B*T][C]
  bf16_t* Wqb  = (bf16_t*)(ws + ((size_t)8  << 20));  // 2 MB  (Wq|Wk|Wv contiguous = Wqkv [3072][1024])
  bf16_t* Wkb  = (bf16_t*)(ws + ((size_t)10 << 20));  // 2 MB
  bf16_t* Wvb  = (bf16_t*)(ws + ((size_t)12 << 20));  // 2 MB
  bf16_t* Wpb  = (bf16_t*)(ws + ((size_t)14 << 20));  // 2 MB
  bf16_t* qo   = (bf16_t*)(ws + ((size_t)16 << 20));  // 8 MB  [B,H,T,D] (pre-scaled, exp2 domain)
  bf16_t* ko   = (bf16_t*)(ws + ((size_t)24 << 20));  // 8 MB  [B,H,T,D]
  bf16_t* vto  = (bf16_t*)(ws + ((size_t)32 << 20));  // 8 MB  [B,H,D,T]
  bf16_t* attb = (bf16_t*)(ws + ((size_t)40 << 20));  // 8 MB  [B,T,H*D]

  cast_all<<<8192, 256, 0, stream>>>(X, Wq, Wk, Wv, Wp, Xb, Wqb, Wkb, Wvb, Wpb);
  gemm_qkv<<<dim3(32, 24), 256, 0, stream>>>(Xb, Wqb, qo, ko, vto);
  attn_fwd<<<1024, 256, 0, stream>>>(qo, ko, vto, attb);
  gemm_proj<<<dim3(32, 8), 256, 0, stream>>>(attb, Wpb, bp, out);
}